// Round 10
// baseline (824.587 us; speedup 1.0000x reference)
//
#include <hip/hip_runtime.h>
#include <hip/hip_bf16.h>
#include <math.h>

#define BB 32
#define SS 1024
#define DD 1024

typedef __bf16 bf16_t;
typedef __bf16 bf16x4 __attribute__((ext_vector_type(4)));
typedef __bf16 bf16x8 __attribute__((ext_vector_type(8)));
typedef float f32x4 __attribute__((ext_vector_type(4)));

// async global -> LDS, 16B per lane. LDS pointer must be wave-uniform;
// HW writes lds_base + lane*16 (linear).
__device__ __forceinline__ void gload16(const void* g, void* lds_uniform) {
    __builtin_amdgcn_global_load_lds(
        (const __attribute__((address_space(1))) void*)g,
        (__attribute__((address_space(3))) void*)lds_uniform, 16, 0, 0);
}

// ---------------------------------------------------------------------------
// Stage one 128x32 bf16 tile (8 KB) into an LDS slot: 2 gloads/thread,
// 256 threads. LDS row-major [128][64B = 4 chunks of 16B], chunk-XOR
// swizzled: LDS slot (row,c) holds global chunk c ^ ((row>>1)&3)
// (0-conflict verified round 8; same formula). Write side pre-swizzles the
// global source; LDS dest stays linear (thread t -> byte t*16).
// Second gload covers rows +64: (r+64)>>1 & 3 unchanged.
// ---------------------------------------------------------------------------
__device__ __forceinline__ void stage32(const bf16_t* __restrict__ src,
                                        int row0, int k0, char* slot, int tid) {
    const int r = tid >> 2;                             // 0..63
    const int c = ((tid & 3) ^ ((tid >> 3) & 3)) * 8;   // swizzled source chunk
    char* d = slot + (tid >> 6) * 1024;                 // wave-uniform dest
    const bf16_t* s = src + (size_t)(row0 + r) * DD + k0 + c;
    gload16(s, d);
    gload16(s + (size_t)64 * DD, d + 4096);             // rows 64..127
}

#define VM8  asm volatile("s_waitcnt vmcnt(8)" ::: "memory")
#define VM4  asm volatile("s_waitcnt vmcnt(4)" ::: "memory")
#define VM0  asm volatile("s_waitcnt vmcnt(0)" ::: "memory")
#define BARR asm volatile("s_barrier" ::: "memory")

// pass selection over 96 K-tiles (3 split passes x 32 tiles of K=32):
// pass 0: Ah*Bh, pass 1: Ah*Bl, pass 2: Al*Bh
#define SEL_A(u) ((((u) >> 5) == 2) ? Alo : Ahi)
#define SEL_B(u) ((((u) >> 5) == 1) ? Blo : Bhi)
#define K0OF(u)  (((u) & 31) * 32)

// One K=32 tile on static slot s (coarse round-8 structure): stage A(u+3),
// stage B(u+3), read 4 B-frags + 4 A-frags, 16 MFMA. Caller appends
// VM8 + publishing barrier.
#define TILE32(u, s, DOST) do {                                               \
    if (DOST) {                                                               \
        stage32(SEL_A((u)+3), rowA, K0OF((u)+3),                              \
                AslR + ((((u)+3)&3) * 8192), tid);                            \
        stage32(SEL_B((u)+3), rowB, K0OF((u)+3),                              \
                BslR + ((((u)+3)&3) * 8192), tid);                            \
    }                                                                         \
    bf16x8 bfr[4], af[4];                                                     \
    _Pragma("unroll") for (int fc = 0; fc < 4; ++fc)                          \
        bfr[fc] = *(const bf16x8*)(Bbase##s + fc * 1024);                     \
    _Pragma("unroll") for (int fr = 0; fr < 4; ++fr)                          \
        af[fr] = *(const bf16x8*)(Abase##s + fr * 1024);                      \
    _Pragma("unroll") for (int fr = 0; fr < 4; ++fr)                          \
        _Pragma("unroll") for (int fc = 0; fc < 4; ++fc)                      \
            acc[fr][fc] = __builtin_amdgcn_mfma_f32_16x16x32_bf16(            \
                af[fr], bfr[fc], acc[fr][fc], 0, 0, 0);                       \
} while (0)

// ---------------------------------------------------------------------------
// 96-K-tile ring loop (4 slots of 8 KB per operand, prefetch depth 3,
// counted vmcnt). Ring discipline: stage(u+3) targets slot (u+3)&3 =
// (u-1)&3 whose reads finished before tile (u-1)'s closing barrier; VM8 at
// tile u's end waits only for tile u+1's 4 gloads (issued at tile u-2).
// ---------------------------------------------------------------------------
__device__ __forceinline__ void kloop_ring(
    const bf16_t* __restrict__ Ahi, const bf16_t* __restrict__ Alo,
    const bf16_t* __restrict__ Bhi, const bf16_t* __restrict__ Blo,
    int rowA, int rowB, int tid, int lane, int wm, int wn,
    char* AslR, char* BslR, f32x4 (*acc)[4])
{
    // per-lane read base: row (lane&15), k-chunk (lane>>4), chunk-XOR swizzle
    const int aoff = (lane & 15) * 64 + (((lane >> 4) ^ ((lane >> 1) & 3)) * 16);
    const char* Abase0 = AslR + wm * 4096 + aoff;
    const char* Abase1 = Abase0 + 8192;
    const char* Abase2 = Abase0 + 16384;
    const char* Abase3 = Abase0 + 24576;
    const char* Bbase0 = BslR + wn * 4096 + aoff;
    const char* Bbase1 = Bbase0 + 8192;
    const char* Bbase2 = Bbase0 + 16384;
    const char* Bbase3 = Bbase0 + 24576;

    // prologue: stage tiles 0,1,2 into slots 0,1,2 (12 gloads in flight)
    stage32(SEL_A(0), rowA, K0OF(0), AslR, tid);
    stage32(SEL_B(0), rowB, K0OF(0), BslR, tid);
    stage32(SEL_A(1), rowA, K0OF(1), AslR + 8192, tid);
    stage32(SEL_B(1), rowB, K0OF(1), BslR + 8192, tid);
    stage32(SEL_A(2), rowA, K0OF(2), AslR + 16384, tid);
    stage32(SEL_B(2), rowB, K0OF(2), BslR + 16384, tid);
    VM8;   // tile 0 landed (8 = tiles 1,2 still outstanding)
    BARR;

    for (int i = 0; i < 23; ++i) {
        const int u0 = i * 4;
        TILE32(u0 + 0, 0, true); VM8; BARR;
        TILE32(u0 + 1, 1, true); VM8; BARR;
        TILE32(u0 + 2, 2, true); VM8; BARR;
        TILE32(u0 + 3, 3, true); VM8; BARR;
    }
    // tail: tiles 92..95 (92 stages tile 95; then drain 8 -> 4 -> 0)
    TILE32(92, 0, true);  VM8; BARR;
    TILE32(93, 1, false); VM4; BARR;
    TILE32(94, 2, false); VM0; BARR;
    TILE32(95, 3, false);
}

// ---------------------------------------------------------------------------
// y = x * M  (B operand = Mt[n,k] = M[k,n]); split-precision 3-pass.
// grid 2048, 256 threads (4 waves 2x2), 64 KB LDS -> 2 blocks/CU.
// XCD pinning: n-tile = bid&7 (one 512 KB Mt panel per XCD L2), m = bid>>3.
// ---------------------------------------------------------------------------
__global__ __launch_bounds__(256, 2) void gemm_y_128(
    const bf16_t* __restrict__ xh, const bf16_t* __restrict__ xl,
    const bf16_t* __restrict__ Mth, const bf16_t* __restrict__ Mtl,
    bf16_t* __restrict__ out_hi, bf16_t* __restrict__ out_lo)
{
    __shared__ __align__(16) bf16_t Asl[4][128 * 32];
    __shared__ __align__(16) bf16_t Bsl[4][128 * 32];
    const int tid = threadIdx.x;
    const int lane = tid & 63, wid = tid >> 6;
    const int wm = wid >> 1, wn = wid & 1;
    const int n0 = (blockIdx.x & 7) * 128;
    const int m0 = (blockIdx.x >> 3) * 128;

    f32x4 acc[4][4] = {};
    kloop_ring(xh, xl, Mth, Mtl, m0, n0, tid, lane, wm, wn,
               (char*)Asl, (char*)Bsl, acc);

    // epilogue: C/D frag layout col=lane&15, row=(lane>>4)*4+r
    const int rbase = (lane >> 4) * 4;
    const int cbase = lane & 15;
    #pragma unroll
    for (int fr = 0; fr < 4; ++fr) {
        #pragma unroll
        for (int fc = 0; fc < 4; ++fc) {
            const int n = n0 + wn * 64 + fc * 16 + cbase;
            #pragma unroll
            for (int r = 0; r < 4; ++r) {
                const int m = m0 + wm * 64 + fr * 16 + rbase + r;
                float vf = acc[fr][fc][r];
                bf16_t h = (bf16_t)vf;
                out_hi[(size_t)m * DD + n] = h;
                out_lo[(size_t)m * DD + n] = (bf16_t)(vf - (float)h);
            }
        }
    }
}

// ---------------------------------------------------------------------------
// Scores (per batch): s[b,srow] += sum_t tanh(y.x + alpha_s + beta_t + c)*v[t]
// grid 2048: t-tile = bid&7 (XCD-pinned), idx = bid>>3: b = idx>>3, s = idx&7.
// ---------------------------------------------------------------------------
__global__ __launch_bounds__(256, 2) void gemm_scores_128(
    const bf16_t* __restrict__ yh, const bf16_t* __restrict__ yl,
    const bf16_t* __restrict__ xh, const bf16_t* __restrict__ xl,
    const float* __restrict__ v, const float* __restrict__ alpha,
    const float* __restrict__ beta, const float* __restrict__ cbuf,
    float* __restrict__ sbuf)
{
    __shared__ __align__(16) bf16_t Asl[4][128 * 32];
    __shared__ __align__(16) bf16_t Bsl[4][128 * 32];
    const int tid = threadIdx.x;
    const int lane = tid & 63, wid = tid >> 6;
    const int wm = wid >> 1, wn = wid & 1;
    const int t0 = (blockIdx.x & 7) * 128;
    const int idx = blockIdx.x >> 3;
    const int b  = idx >> 3;
    const int s0 = (idx & 7) * 128;
    const size_t boff = (size_t)b * SS * DD;

    f32x4 acc[4][4] = {};
    kloop_ring(yh + boff, yl + boff, xh + boff, xl + boff, s0, t0,
               tid, lane, wm, wn, (char*)Asl, (char*)Bsl, acc);

    // epilogue: tanh(score + alpha_s + beta_t + c)*v[t]; 16-lane col reduce.
    const float c0 = cbuf[0];
    const int rbase = (lane >> 4) * 4;
    const int cbase = lane & 15;
    float bet[4], vv[4];
    #pragma unroll
    for (int fc = 0; fc < 4; ++fc) {
        const int t = t0 + wn * 64 + fc * 16 + cbase;
        bet[fc] = beta[b * SS + t];
        vv[fc]  = v[t];
    }
    #pragma unroll
    for (int fr = 0; fr < 4; ++fr) {
        #pragma unroll
        for (int r = 0; r < 4; ++r) {
            const int srow = s0 + wm * 64 + fr * 16 + rbase + r;
            const float al = alpha[b * SS + srow] + c0;
            float p = 0.f;
            #pragma unroll
            for (int fc = 0; fc < 4; ++fc)
                p += tanhf(acc[fr][fc][r] + al + bet[fc]) * vv[fc];
            p += __shfl_xor(p, 1);
            p += __shfl_xor(p, 2);
            p += __shfl_xor(p, 4);
            p += __shfl_xor(p, 8);
            if (cbase == 0) atomicAdd(&sbuf[b * SS + srow], p);
        }
    }
}

// ---------------------------------------------------------------------------
// split fp32 -> (hi, lo) bf16.  hi = bf16(f), lo = bf16(f - hi).
// ---------------------------------------------------------------------------
__global__ __launch_bounds__(256) void split_fp32(
    const float* __restrict__ src, bf16_t* __restrict__ hi,
    bf16_t* __restrict__ lo, int n4)
{
    for (int idx = blockIdx.x * 256 + threadIdx.x; idx < n4;
         idx += gridDim.x * 256) {
        float4 f = ((const float4*)src)[idx];
        bf16x4 h, l;
        h.x = (bf16_t)f.x; h.y = (bf16_t)f.y; h.z = (bf16_t)f.z; h.w = (bf16_t)f.w;
        l.x = (bf16_t)(f.x - (float)h.x);
        l.y = (bf16_t)(f.y - (float)h.y);
        l.z = (bf16_t)(f.z - (float)h.z);
        l.w = (bf16_t)(f.w - (float)h.w);
        ((bf16x4*)hi)[idx] = h;
        ((bf16x4*)lo)[idx] = l;
    }
}

// ---------------------------------------------------------------------------
// split x -> hi/lo AND per-row alpha = x_row.avec, beta = x_row.bvec.
// Launch with grid = 2048 exactly (one row per block-iteration).
// ---------------------------------------------------------------------------
__global__ __launch_bounds__(256) void split_x_ab(
    const float* __restrict__ src, bf16_t* __restrict__ hi,
    bf16_t* __restrict__ lo, const float* __restrict__ avec,
    const float* __restrict__ bvec, float* __restrict__ alpha,
    float* __restrict__ beta)
{
    __shared__ float reda[4], redb[4];
    const int tid = threadIdx.x;
    const int lane = tid & 63, wave = tid >> 6;
    const float4 av = ((const float4*)avec)[tid];
    const float4 bv = ((const float4*)bvec)[tid];
    const int n4 = BB * SS * DD / 4;
    for (int idx = blockIdx.x * 256 + tid; idx < n4; idx += gridDim.x * 256) {
        float4 f = ((const float4*)src)[idx];
        bf16x4 h, l;
        h.x = (bf16_t)f.x; h.y = (bf16_t)f.y; h.z = (bf16_t)f.z; h.w = (bf16_t)f.w;
        l.x = (bf16_t)(f.x - (float)h.x);
        l.y = (bf16_t)(f.y - (float)h.y);
        l.z = (bf16_t)(f.z - (float)h.z);
        l.w = (bf16_t)(f.w - (float)h.w);
        ((bf16x4*)hi)[idx] = h;
        ((bf16x4*)lo)[idx] = l;

        float pa = f.x * av.x + f.y * av.y + f.z * av.z + f.w * av.w;
        float pb = f.x * bv.x + f.y * bv.y + f.z * bv.z + f.w * bv.w;
        #pragma unroll
        for (int off = 32; off; off >>= 1) {
            pa += __shfl_xor(pa, off);
            pb += __shfl_xor(pb, off);
        }
        if (lane == 0) { reda[wave] = pa; redb[wave] = pb; }
        __syncthreads();
        if (tid == 0) {
            const int row = idx >> 8;
            alpha[row] = reda[0] + reda[1] + reda[2] + reda[3];
            beta[row]  = redb[0] + redb[1] + redb[2] + redb[3];
        }
        __syncthreads();
    }
}

// ---------------------------------------------------------------------------
// avec[d] = sum_e Wq[e,d]*bk[e] (z=0), bvec[d] = sum_e Wk[e,d]*bq[e] (z=1).
// ---------------------------------------------------------------------------
__global__ __launch_bounds__(256) void bias_gemv(
    const float* __restrict__ Wq, const float* __restrict__ Wk,
    const float* __restrict__ bq, const float* __restrict__ bk,
    float* __restrict__ avec, float* __restrict__ bvec)
{
    const float* W   = blockIdx.z ? Wk : Wq;
    const float* bb  = blockIdx.z ? bq : bk;
    float* outv      = blockIdx.z ? bvec : avec;
    const int d  = blockIdx.x * 256 + threadIdx.x;
    const int e0 = blockIdx.y * 64;
    float s = 0.f;
    for (int e = e0; e < e0 + 64; ++e) s += W[(size_t)e * DD + d] * bb[e];
    atomicAdd(&outv[d], s);
}

__global__ __launch_bounds__(256) void dot_c(
    const float* __restrict__ bq, const float* __restrict__ bk,
    float* __restrict__ cbuf)
{
    __shared__ float red[4];
    const int tid = threadIdx.x, lane = tid & 63, wave = tid >> 6;
    float s = 0.f;
    for (int e = tid; e < DD; e += 256) s += bq[e] * bk[e];
    #pragma unroll
    for (int off = 32; off; off >>= 1) s += __shfl_xor(s, off);
    if (lane == 0) red[wave] = s;
    __syncthreads();
    if (tid == 0) cbuf[0] = red[0] + red[1] + red[2] + red[3];
}

// ---------------------------------------------------------------------------
// Mt[n,k] = sum_e Wk[e,n] * Wq[e,k]   (fp32 VALU, 64x64 tile)
// ---------------------------------------------------------------------------
__global__ __launch_bounds__(256) void mt_f32(
    const float* __restrict__ Wk, const float* __restrict__ Wq,
    float* __restrict__ Mt)
{
    __shared__ float Us[16][68];
    __shared__ float Vs[16][68];
    const int tid = threadIdx.x;
    const int tx = tid & 15, ty = tid >> 4;
    const int i0 = blockIdx.y * 64;
    const int j0 = blockIdx.x * 64;
    float acc[4][4] = {};
    for (int e0 = 0; e0 < DD; e0 += 16) {
        #pragma unroll
        for (int r = 0; r < 4; ++r) {
            const int kk = (tid >> 6) + r * 4;
            const int cc = tid & 63;
            Us[kk][cc] = Wk[(size_t)(e0 + kk) * DD + i0 + cc];
            Vs[kk][cc] = Wq[(size_t)(e0 + kk) * DD + j0 + cc];
        }
        __syncthreads();
        #pragma unroll
        for (int kk = 0; kk < 16; ++kk) {
            float4 a = *(const float4*)&Us[kk][ty * 4];
            float4 w = *(const float4*)&Vs[kk][tx * 4];
            acc[0][0] += a.x * w.x; acc[0][1] += a.x * w.y; acc[0][2] += a.x * w.z; acc[0][3] += a.x * w.w;
            acc[1][0] += a.y * w.x; acc[1][1] += a.y * w.y; acc[1][2] += a.y * w.z; acc[1][3] += a.y * w.w;
            acc[2][0] += a.z * w.x; acc[2][1] += a.z * w.y; acc[2][2] += a.z * w.z; acc[2][3] += a.z * w.w;
            acc[3][0] += a.w * w.x; acc[3][1] += a.w * w.y; acc[3][2] += a.w * w.z; acc[3][3] += a.w * w.w;
        }
        __syncthreads();
    }
    #pragma unroll
    for (int i = 0; i < 4; ++i)
        #pragma unroll
        for (int j = 0; j < 4; ++j)
            Mt[(size_t)(i0 + ty * 4 + i) * DD + j0 + tx * 4 + j] = acc[i][j];
}

// ---------------------------------------------------------------------------
// softmax over S per batch
// ---------------------------------------------------------------------------
__global__ __launch_bounds__(256) void softmax_rows(
    const float* __restrict__ sbuf, float* __restrict__ wbuf)
{
    const int b = blockIdx.x, tid = threadIdx.x;
    const int wave = tid >> 6, lane = tid & 63;
    __shared__ float redm[4];
    __shared__ float redsum[4];

    float vals[4];
    float mx = -1e30f;
    #pragma unroll
    for (int i = 0; i < 4; ++i) {
        vals[i] = sbuf[b * SS + i * 256 + tid];
        mx = fmaxf(mx, vals[i]);
    }
    #pragma unroll
    for (int off = 32; off; off >>= 1) mx = fmaxf(mx, __shfl_xor(mx, off));
    if (lane == 0) redm[wave] = mx;
    __syncthreads();
    mx = fmaxf(fmaxf(redm[0], redm[1]), fmaxf(redm[2], redm[3]));

    float sum = 0.f;
    #pragma unroll
    for (int i = 0; i < 4; ++i) { vals[i] = expf(vals[i] - mx); sum += vals[i]; }
    #pragma unroll
    for (int off = 32; off; off >>= 1) sum += __shfl_xor(sum, off);
    if (lane == 0) redsum[wave] = sum;
    __syncthreads();
    sum = redsum[0] + redsum[1] + redsum[2] + redsum[3];

    float inv = 1.0f / sum;
    #pragma unroll
    for (int i = 0; i < 4; ++i) wbuf[b * SS + i * 256 + tid] = vals[i] * inv;
}

// ---------------------------------------------------------------------------
// out[b,d] = sum_s w[b,s] * x[b,s,d]
// ---------------------------------------------------------------------------
__global__ __launch_bounds__(256) void weighted_sum(
    const float* __restrict__ x, const float* __restrict__ wbuf,
    float* __restrict__ out)
{
    __shared__ float wl[SS];
    const int b = blockIdx.y;
    const int d = blockIdx.x * 256 + threadIdx.x;
    for (int i = threadIdx.x; i < SS; i += 256) wl[i] = wbuf[b * SS + i];
    __syncthreads();

    const float* xb = x + (size_t)b * SS * DD + d;
    float acc = 0.f;
    for (int s = 0; s < SS; ++s) acc += wl[s] * xb[(size_t)s * DD];
    out[b * DD + d] = acc;
}

// ---------------------------------------------------------------------------
extern "C" void kernel_launch(void* const* d_in, const int* in_sizes, int n_in,
                              void* d_out, int out_size, void* d_ws, size_t ws_size,
                              hipStream_t stream) {
    const float* x  = (const float*)d_in[0];
    const float* Wq = (const float*)d_in[1];
    const float* bq = (const float*)d_in[2];
    const float* Wk = (const float*)d_in[3];
    const float* bk = (const float*)d_in[4];
    const float* v  = (const float*)d_in[5];
    float* out = (float*)d_out;

    const size_t nx = (size_t)BB * SS * DD;   // 33,554,432
    const size_t nw = (size_t)DD * DD;        // 1,048,576

    dim3 blk(256);

    // workspace layout (verified to fit in rounds 4-9)
    char* p = (char*)d_ws;
    bf16_t* xh  = (bf16_t*)p;   p += nx * 2;
    bf16_t* xl  = (bf16_t*)p;   p += nx * 2;
    bf16_t* yh  = (bf16_t*)p;   p += nx * 2;
    bf16_t* yl  = (bf16_t*)p;   p += nx * 2;
    float*  Mt  = (float*)p;    p += nw * 4;
    bf16_t* Mth = (bf16_t*)p;   p += nw * 2;
    bf16_t* Mtl = (bf16_t*)p;   p += nw * 2;
    float*  avec = (float*)p;   p += 4096;
    float*  bvec = (float*)p;   p += 4096;
    float*  cbuf = (float*)p;   p += 16;
    float*  alpha = (float*)p;  p += (size_t)BB * SS * 4;
    float*  beta  = (float*)p;  p += (size_t)BB * SS * 4;
    float*  sbuf  = (float*)p;  p += (size_t)BB * SS * 4;
    float*  wbuf  = (float*)p;

    hipMemsetAsync(sbuf, 0, (size_t)BB * SS * sizeof(float), stream);
    hipMemsetAsync(avec, 0, 4096 * 2, stream);

    bias_gemv<<<dim3(4, 16, 2), blk, 0, stream>>>(Wq, Wk, bq, bk, avec, bvec);
    dot_c<<<1, blk, 0, stream>>>(bq, bk, cbuf);
    split_x_ab<<<2048, blk, 0, stream>>>(x, xh, xl, avec, bvec, alpha, beta);
    mt_f32<<<dim3(16, 16), blk, 0, stream>>>(Wk, Wq, Mt);
    split_fp32<<<512, blk, 0, stream>>>(Mt, Mth, Mtl, (int)(nw / 4));

    gemm_y_128<<<2048, blk, 0, stream>>>(xh, xl, Mth, Mtl, yh, yl);
    gemm_scores_128<<<2048, blk, 0, stream>>>(yh, yl, xh, xl, v,
                                              alpha, beta, cbuf, sbuf);

    softmax_rows<<<BB, blk, 0, stream>>>(sbuf, wbuf);
    dim3 g4(DD / 256, BB);
    weighted_sum<<<g4, blk, 0, stream>>>(x, wbuf, out);
}

// Round 11
// 623.909 us; speedup vs baseline: 1.3216x; 1.3216x over previous
//
#include <hip/hip_runtime.h>
#include <hip/hip_bf16.h>
#include <math.h>

#define BB 32
#define SS 1024
#define DD 1024

typedef __bf16 bf16_t;
typedef __bf16 bf16x2 __attribute__((ext_vector_type(2)));
typedef __bf16 bf16x4 __attribute__((ext_vector_type(4)));
typedef __bf16 bf16x8 __attribute__((ext_vector_type(8)));
typedef float f32x4 __attribute__((ext_vector_type(4)));

// async global -> LDS, 16B per lane. LDS pointer must be wave-uniform;
// HW writes lds_base + lane*16 (linear).
__device__ __forceinline__ void gload16(const void* g, void* lds_uniform) {
    __builtin_amdgcn_global_load_lds(
        (const __attribute__((address_space(1))) void*)g,
        (__attribute__((address_space(3))) void*)lds_uniform, 16, 0, 0);
}

// ---------------------------------------------------------------------------
// Stage one 256x32 bf16 tile (16 KB) into an LDS slot: 2 gloads/thread.
// LDS row-major [256][64B = 4 chunks of 16B], chunk-XOR swizzled:
// LDS slot (row, c) holds global chunk c ^ ((row>>1)&3) (verified 0
// bank conflicts, round 8). Write side pre-swizzles the global source.
// ---------------------------------------------------------------------------
__device__ __forceinline__ void stage32(const bf16_t* __restrict__ src,
                                        int row0, int k0, char* slot, int tid) {
    const int r = tid >> 2;
    const int c = ((tid & 3) ^ ((tid >> 3) & 3)) * 8;   // swizzled source chunk
    char* d = slot + (tid >> 6) * 1024;   // wave-uniform dest
    const bf16_t* s = src + (size_t)(row0 + r) * DD + k0 + c;
    gload16(s, d);
    gload16(s + (size_t)128 * DD, d + 8192);
}

#define VM8  asm volatile("s_waitcnt vmcnt(8)" ::: "memory")
#define VM4  asm volatile("s_waitcnt vmcnt(4)" ::: "memory")
#define VM0  asm volatile("s_waitcnt vmcnt(0)" ::: "memory")
#define BARR asm volatile("s_barrier" ::: "memory")

// pass selection over 96 K-tiles (3 split passes x 32 tiles of K=32):
// pass 0: Ah*Bh, pass 1: Ah*Bl, pass 2: Al*Bh
#define SEL_A(u) ((((u) >> 5) == 2) ? Alo : Ahi)
#define SEL_B(u) ((((u) >> 5) == 1) ? Blo : Bhi)
#define K0OF(u)  (((u) & 31) * 32)

// One K=32 tile on static slot s (round-8 coarse structure): stage A(u+3),
// read 4 B-frags + 4 A-frags, 16 MFMA, stage B(u+3), read 4 A-frags
// (rows 64..127), 16 MFMA. Caller appends VM8 + publishing barrier.
#define TILE32(u, s, DOST) do {                                               \
    if (DOST) stage32(SEL_A((u)+3), rowA, K0OF((u)+3),                        \
                      AslR + ((((u)+3)&3) * 16384), tid);                     \
    bf16x8 bfr[4], af[4];                                                     \
    _Pragma("unroll") for (int fc = 0; fc < 4; ++fc)                          \
        bfr[fc] = *(const bf16x8*)(Bbase##s + fc * 1024);                     \
    _Pragma("unroll") for (int fr = 0; fr < 4; ++fr)                          \
        af[fr] = *(const bf16x8*)(Abase##s + fr * 1024);                      \
    _Pragma("unroll") for (int fr = 0; fr < 4; ++fr)                          \
        _Pragma("unroll") for (int fc = 0; fc < 4; ++fc)                      \
            acc[fr][fc] = __builtin_amdgcn_mfma_f32_16x16x32_bf16(            \
                af[fr], bfr[fc], acc[fr][fc], 0, 0, 0);                       \
    if (DOST) stage32(SEL_B((u)+3), rowB, K0OF((u)+3),                        \
                      BslR + ((((u)+3)&3) * 16384), tid);                     \
    _Pragma("unroll") for (int fr = 0; fr < 4; ++fr)                          \
        af[fr] = *(const bf16x8*)(Abase##s + 4096 + fr * 1024);               \
    _Pragma("unroll") for (int fr = 0; fr < 4; ++fr)                          \
        _Pragma("unroll") for (int fc = 0; fc < 4; ++fc)                      \
            acc[4+fr][fc] = __builtin_amdgcn_mfma_f32_16x16x32_bf16(          \
                af[fr], bfr[fc], acc[4+fr][fc], 0, 0, 0);                     \
} while (0)

// ---------------------------------------------------------------------------
// 96-K-tile ring loop (4 slots, prefetch depth 3, counted vmcnt).
// Ring discipline: stage(u+3) targets slot (u+3)&3 = (u-1)&3 whose reads
// finished before tile (u-1)'s closing barrier; VM8 at tile u's end waits
// only for tile u+1's 4 gloads (issued during tile u-2).
// ---------------------------------------------------------------------------
__device__ __forceinline__ void kloop_ring(
    const bf16_t* __restrict__ Ahi, const bf16_t* __restrict__ Alo,
    const bf16_t* __restrict__ Bhi, const bf16_t* __restrict__ Blo,
    int rowA, int rowB, int tid, int lane, int wm, int wn,
    char* AslR, char* BslR, f32x4 (*acc)[4])
{
    // per-lane read base: row (lane&15), k-chunk (lane>>4), chunk-XOR swizzle
    const int aoff = (lane & 15) * 64 + (((lane >> 4) ^ ((lane >> 1) & 3)) * 16);
    const char* Abase0 = AslR + wm * 8192 + aoff;
    const char* Abase1 = Abase0 + 16384;
    const char* Abase2 = Abase0 + 32768;
    const char* Abase3 = Abase0 + 49152;
    const char* Bbase0 = BslR + wn * 4096 + aoff;
    const char* Bbase1 = Bbase0 + 16384;
    const char* Bbase2 = Bbase0 + 32768;
    const char* Bbase3 = Bbase0 + 49152;

    // prologue: stage tiles 0,1,2 into slots 0,1,2 (12 gloads in flight)
    stage32(SEL_A(0), rowA, K0OF(0), AslR, tid);
    stage32(SEL_B(0), rowB, K0OF(0), BslR, tid);
    stage32(SEL_A(1), rowA, K0OF(1), AslR + 16384, tid);
    stage32(SEL_B(1), rowB, K0OF(1), BslR + 16384, tid);
    stage32(SEL_A(2), rowA, K0OF(2), AslR + 32768, tid);
    stage32(SEL_B(2), rowB, K0OF(2), BslR + 32768, tid);
    VM8;   // tile 0 landed (8 = tiles 1,2 still outstanding)
    BARR;

    for (int i = 0; i < 23; ++i) {
        const int u0 = i * 4;
        TILE32(u0 + 0, 0, true); VM8; BARR;
        TILE32(u0 + 1, 1, true); VM8; BARR;
        TILE32(u0 + 2, 2, true); VM8; BARR;
        TILE32(u0 + 3, 3, true); VM8; BARR;
    }
    // tail: tiles 92..95 (92 stages tile 95; then drain 8 -> 4 -> 0)
    TILE32(92, 0, true);  VM8; BARR;
    TILE32(93, 1, false); VM4; BARR;
    TILE32(94, 2, false); VM0; BARR;
    TILE32(95, 3, false);
}

// ---------------------------------------------------------------------------
// y = x * M  (B operand = Mt[n,k] = M[k,n]); split-precision 3-pass.
// grid 512 (1-D, XCD-swizzled): m-tile = lin>>2 (128), n-tile = lin&3 (4).
// ---------------------------------------------------------------------------
__global__ __launch_bounds__(512, 2) void gemm_y_256(
    const bf16_t* __restrict__ xh, const bf16_t* __restrict__ xl,
    const bf16_t* __restrict__ Mth, const bf16_t* __restrict__ Mtl,
    bf16_t* __restrict__ out_hi, bf16_t* __restrict__ out_lo)
{
    __shared__ __align__(16) bf16_t Asl[4][256 * 32];
    __shared__ __align__(16) bf16_t Bsl[4][256 * 32];
    const int tid = threadIdx.x;
    const int lane = tid & 63, wid = tid >> 6;
    const int wm = wid >> 2, wn = wid & 3;
    const int lin = (blockIdx.x & 7) * 64 + (blockIdx.x >> 3);
    const int m0 = (lin >> 2) * 256;
    const int n0 = (lin & 3) * 256;

    f32x4 acc[8][4] = {};
    kloop_ring(xh, xl, Mth, Mtl, m0, n0, tid, lane, wm, wn,
               (char*)Asl, (char*)Bsl, acc);

    // epilogue: C/D frag layout col=lane&15, row=(lane>>4)*4+r
    const int rbase = (lane >> 4) * 4;
    const int cbase = lane & 15;
    #pragma unroll
    for (int fr = 0; fr < 8; ++fr) {
        #pragma unroll
        for (int fc = 0; fc < 4; ++fc) {
            const int n = n0 + wn * 64 + fc * 16 + cbase;
            #pragma unroll
            for (int r = 0; r < 4; ++r) {
                const int m = m0 + wm * 128 + fr * 16 + rbase + r;
                float vf = acc[fr][fc][r];
                bf16_t h = (bf16_t)vf;
                out_hi[(size_t)m * DD + n] = h;
                out_lo[(size_t)m * DD + n] = (bf16_t)(vf - (float)h);
            }
        }
    }
}

// ---------------------------------------------------------------------------
// Scores (per batch): s[b,srow] += sum_t tanh(y.x + alpha_s + beta_t + c)*v[t]
// grid 512 (XCD-swizzled): t-tile = lin&3, s-tile = (lin>>2)&3, b = lin>>4.
// ---------------------------------------------------------------------------
__global__ __launch_bounds__(512, 2) void gemm_scores_256(
    const bf16_t* __restrict__ yh, const bf16_t* __restrict__ yl,
    const bf16_t* __restrict__ xh, const bf16_t* __restrict__ xl,
    const float* __restrict__ v, const float* __restrict__ alpha,
    const float* __restrict__ beta, const float* __restrict__ cbuf,
    float* __restrict__ sbuf)
{
    __shared__ __align__(16) bf16_t Asl[4][256 * 32];
    __shared__ __align__(16) bf16_t Bsl[4][256 * 32];
    const int tid = threadIdx.x;
    const int lane = tid & 63, wid = tid >> 6;
    const int wm = wid >> 2, wn = wid & 3;
    const int lin = (blockIdx.x & 7) * 64 + (blockIdx.x >> 3);
    const int t0 = (lin & 3) * 256;
    const int s0 = ((lin >> 2) & 3) * 256;
    const int b  = lin >> 4;
    const size_t boff = (size_t)b * SS * DD;

    f32x4 acc[8][4] = {};
    kloop_ring(yh + boff, yl + boff, xh + boff, xl + boff, s0, t0,
               tid, lane, wm, wn, (char*)Asl, (char*)Bsl, acc);

    // epilogue: tanh(score + alpha_s + beta_t + c)*v[t]; 16-lane col reduce.
    const float c0 = cbuf[0];
    const int rbase = (lane >> 4) * 4;
    const int cbase = lane & 15;
    float bet[4], vv[4];
    #pragma unroll
    for (int fc = 0; fc < 4; ++fc) {
        const int t = t0 + wn * 64 + fc * 16 + cbase;
        bet[fc] = beta[b * SS + t];
        vv[fc]  = v[t];
    }
    #pragma unroll
    for (int fr = 0; fr < 8; ++fr) {
        #pragma unroll
        for (int r = 0; r < 4; ++r) {
            const int srow = s0 + wm * 128 + fr * 16 + rbase + r;
            const float al = alpha[b * SS + srow] + c0;
            float p = 0.f;
            #pragma unroll
            for (int fc = 0; fc < 4; ++fc)
                p += tanhf(acc[fr][fc][r] + al + bet[fc]) * vv[fc];
            p += __shfl_xor(p, 1);
            p += __shfl_xor(p, 2);
            p += __shfl_xor(p, 4);
            p += __shfl_xor(p, 8);
            if (cbase == 0) atomicAdd(&sbuf[b * SS + srow], p);
        }
    }
}

// ---------------------------------------------------------------------------
// split x -> hi/lo bf16 AND per-row alpha = x_row.avec, beta = x_row.bvec.
// One WAVE per row (no __syncthreads): lane handles 4 float4 at stride 64,
// avec/bvec slices hoisted to registers. grid 2048 x 4 waves = 8192
// rows/pass, 4 passes over 32768 rows.
// ---------------------------------------------------------------------------
__global__ __launch_bounds__(256) void split_x_ab(
    const float* __restrict__ src, bf16_t* __restrict__ hi,
    bf16_t* __restrict__ lo, const float* __restrict__ avec,
    const float* __restrict__ bvec, float* __restrict__ alpha,
    float* __restrict__ beta)
{
    const int lane = threadIdx.x & 63, wave = threadIdx.x >> 6;
    float4 av[4], bv[4];
    #pragma unroll
    for (int j = 0; j < 4; ++j) {
        av[j] = ((const float4*)avec)[j * 64 + lane];
        bv[j] = ((const float4*)bvec)[j * 64 + lane];
    }
    for (int row = blockIdx.x * 4 + wave; row < BB * SS; row += 2048 * 4) {
        const float4* xr = (const float4*)(src + (size_t)row * DD);
        bf16x4* hr = (bf16x4*)(hi + (size_t)row * DD);
        bf16x4* lr = (bf16x4*)(lo + (size_t)row * DD);
        float pa = 0.f, pb = 0.f;
        #pragma unroll
        for (int j = 0; j < 4; ++j) {
            float4 f = xr[j * 64 + lane];
            bf16x4 h, l;
            h.x = (bf16_t)f.x; h.y = (bf16_t)f.y;
            h.z = (bf16_t)f.z; h.w = (bf16_t)f.w;
            l.x = (bf16_t)(f.x - (float)h.x);
            l.y = (bf16_t)(f.y - (float)h.y);
            l.z = (bf16_t)(f.z - (float)h.z);
            l.w = (bf16_t)(f.w - (float)h.w);
            hr[j * 64 + lane] = h;
            lr[j * 64 + lane] = l;
            pa += f.x * av[j].x + f.y * av[j].y + f.z * av[j].z + f.w * av[j].w;
            pb += f.x * bv[j].x + f.y * bv[j].y + f.z * bv[j].z + f.w * bv[j].w;
        }
        #pragma unroll
        for (int off = 32; off; off >>= 1) {
            pa += __shfl_xor(pa, off);
            pb += __shfl_xor(pb, off);
        }
        if (lane == 0) { alpha[row] = pa; beta[row] = pb; }
    }
}

// ---------------------------------------------------------------------------
// avec[d] = sum_e Wq[e,d]*bk[e] (z=0), bvec[d] = sum_e Wk[e,d]*bq[e] (z=1).
// ---------------------------------------------------------------------------
__global__ __launch_bounds__(256) void bias_gemv(
    const float* __restrict__ Wq, const float* __restrict__ Wk,
    const float* __restrict__ bq, const float* __restrict__ bk,
    float* __restrict__ avec, float* __restrict__ bvec)
{
    const float* W   = blockIdx.z ? Wk : Wq;
    const float* bb  = blockIdx.z ? bq : bk;
    float* outv      = blockIdx.z ? bvec : avec;
    const int d  = blockIdx.x * 256 + threadIdx.x;
    const int e0 = blockIdx.y * 64;
    float s = 0.f;
    for (int e = e0; e < e0 + 64; ++e) s += W[(size_t)e * DD + d] * bb[e];
    atomicAdd(&outv[d], s);
}

__global__ __launch_bounds__(256) void dot_c(
    const float* __restrict__ bq, const float* __restrict__ bk,
    float* __restrict__ cbuf)
{
    __shared__ float red[4];
    const int tid = threadIdx.x, lane = tid & 63, wave = tid >> 6;
    float s = 0.f;
    for (int e = tid; e < DD; e += 256) s += bq[e] * bk[e];
    #pragma unroll
    for (int off = 32; off; off >>= 1) s += __shfl_xor(s, off);
    if (lane == 0) red[wave] = s;
    __syncthreads();
    if (tid == 0) cbuf[0] = red[0] + red[1] + red[2] + red[3];
}

// ---------------------------------------------------------------------------
// Mt[n,k] = sum_e Wk[e,n] * Wq[e,k] (fp32 VALU, 64x64 tile), fused bf16
// hi/lo split output (replaces separate split_fp32 pass).
// ---------------------------------------------------------------------------
__global__ __launch_bounds__(256) void mt_split(
    const float* __restrict__ Wk, const float* __restrict__ Wq,
    bf16_t* __restrict__ Mth, bf16_t* __restrict__ Mtl)
{
    __shared__ float Us[16][68];
    __shared__ float Vs[16][68];
    const int tid = threadIdx.x;
    const int tx = tid & 15, ty = tid >> 4;
    const int i0 = blockIdx.y * 64;
    const int j0 = blockIdx.x * 64;
    float acc[4][4] = {};
    for (int e0 = 0; e0 < DD; e0 += 16) {
        #pragma unroll
        for (int r = 0; r < 4; ++r) {
            const int kk = (tid >> 6) + r * 4;
            const int cc = tid & 63;
            Us[kk][cc] = Wk[(size_t)(e0 + kk) * DD + i0 + cc];
            Vs[kk][cc] = Wq[(size_t)(e0 + kk) * DD + j0 + cc];
        }
        __syncthreads();
        #pragma unroll
        for (int kk = 0; kk < 16; ++kk) {
            float4 a = *(const float4*)&Us[kk][ty * 4];
            float4 w = *(const float4*)&Vs[kk][tx * 4];
            acc[0][0] += a.x * w.x; acc[0][1] += a.x * w.y; acc[0][2] += a.x * w.z; acc[0][3] += a.x * w.w;
            acc[1][0] += a.y * w.x; acc[1][1] += a.y * w.y; acc[1][2] += a.y * w.z; acc[1][3] += a.y * w.w;
            acc[2][0] += a.z * w.x; acc[2][1] += a.z * w.y; acc[2][2] += a.z * w.z; acc[2][3] += a.z * w.w;
            acc[3][0] += a.w * w.x; acc[3][1] += a.w * w.y; acc[3][2] += a.w * w.z; acc[3][3] += a.w * w.w;
        }
        __syncthreads();
    }
    #pragma unroll
    for (int i = 0; i < 4; ++i) {
        #pragma unroll
        for (int j = 0; j < 4; ++j) {
            const size_t o = (size_t)(i0 + ty * 4 + i) * DD + j0 + tx * 4 + j;
            float vf = acc[i][j];
            bf16_t h = (bf16_t)vf;
            Mth[o] = h;
            Mtl[o] = (bf16_t)(vf - (float)h);
        }
    }
}

// ---------------------------------------------------------------------------
// softmax over S per batch
// ---------------------------------------------------------------------------
__global__ __launch_bounds__(256) void softmax_rows(
    const float* __restrict__ sbuf, float* __restrict__ wbuf)
{
    const int b = blockIdx.x, tid = threadIdx.x;
    const int wave = tid >> 6, lane = tid & 63;
    __shared__ float redm[4];
    __shared__ float redsum[4];

    float vals[4];
    float mx = -1e30f;
    #pragma unroll
    for (int i = 0; i < 4; ++i) {
        vals[i] = sbuf[b * SS + i * 256 + tid];
        mx = fmaxf(mx, vals[i]);
    }
    #pragma unroll
    for (int off = 32; off; off >>= 1) mx = fmaxf(mx, __shfl_xor(mx, off));
    if (lane == 0) redm[wave] = mx;
    __syncthreads();
    mx = fmaxf(fmaxf(redm[0], redm[1]), fmaxf(redm[2], redm[3]));

    float sum = 0.f;
    #pragma unroll
    for (int i = 0; i < 4; ++i) { vals[i] = expf(vals[i] - mx); sum += vals[i]; }
    #pragma unroll
    for (int off = 32; off; off >>= 1) sum += __shfl_xor(sum, off);
    if (lane == 0) redsum[wave] = sum;
    __syncthreads();
    sum = redsum[0] + redsum[1] + redsum[2] + redsum[3];

    float inv = 1.0f / sum;
    #pragma unroll
    for (int i = 0; i < 4; ++i) wbuf[b * SS + i * 256 + tid] = vals[i] * inv;
}

// ---------------------------------------------------------------------------
// out[b,d] += sum over s-chunk of w[b,s] * xh[b,s,d]  (bf16 x, s-split for
// memory parallelism, atomicAdd partials; out zeroed by launcher).
// grid (4, BB): s-chunk = bx*256. Each thread covers 4 columns.
// ---------------------------------------------------------------------------
__global__ __launch_bounds__(256) void weighted_sum(
    const bf16_t* __restrict__ xh, const float* __restrict__ wbuf,
    float* __restrict__ out)
{
    __shared__ float wl[256];
    const int b = blockIdx.y;
    const int s0 = blockIdx.x * 256;
    const int tid = threadIdx.x;
    wl[tid] = wbuf[b * SS + s0 + tid];
    __syncthreads();

    float a0 = 0.f, a1 = 0.f, a2 = 0.f, a3 = 0.f;
    const bf16_t* xb = xh + (size_t)b * SS * DD + (size_t)s0 * DD;
    #pragma unroll 4
    for (int s = 0; s < 256; ++s) {
        const bf16_t* xr = xb + (size_t)s * DD;
        bf16x2 u = *(const bf16x2*)(xr + tid * 2);
        bf16x2 w2 = *(const bf16x2*)(xr + tid * 2 + 512);
        const float w = wl[s];
        a0 += w * (float)u.x;  a1 += w * (float)u.y;
        a2 += w * (float)w2.x; a3 += w * (float)w2.y;
    }
    atomicAdd(&out[b * DD + tid * 2], a0);
    atomicAdd(&out[b * DD + tid * 2 + 1], a1);
    atomicAdd(&out[b * DD + tid * 2 + 512], a2);
    atomicAdd(&out[b * DD + tid * 2 + 513], a3);
}

// ---------------------------------------------------------------------------
extern "C" void kernel_launch(void* const* d_in, const int* in_sizes, int n_in,
                              void* d_out, int out_size, void* d_ws, size_t ws_size,
                              hipStream_t stream) {
    const float* x  = (const float*)d_in[0];
    const float* Wq = (const float*)d_in[1];
    const float* bq = (const float*)d_in[2];
    const float* Wk = (const float*)d_in[3];
    const float* bk = (const float*)d_in[4];
    const float* v  = (const float*)d_in[5];
    float* out = (float*)d_out;

    const size_t nx = (size_t)BB * SS * DD;   // 33,554,432
    const size_t nw = (size_t)DD * DD;        // 1,048,576

    dim3 blk(256);

    // workspace layout
    char* p = (char*)d_ws;
    bf16_t* xh  = (bf16_t*)p;   p += nx * 2;
    bf16_t* xl  = (bf16_t*)p;   p += nx * 2;
    bf16_t* yh  = (bf16_t*)p;   p += nx * 2;
    bf16_t* yl  = (bf16_t*)p;   p += nx * 2;
    bf16_t* Mth = (bf16_t*)p;   p += nw * 2;
    bf16_t* Mtl = (bf16_t*)p;   p += nw * 2;
    float*  avec = (float*)p;   p += 4096;
    float*  bvec = (float*)p;   p += 4096;
    float*  cbuf = (float*)p;   p += 16;
    float*  alpha = (float*)p;  p += (size_t)BB * SS * 4;
    float*  beta  = (float*)p;  p += (size_t)BB * SS * 4;
    float*  sbuf  = (float*)p;  p += (size_t)BB * SS * 4;
    float*  wbuf  = (float*)p;

    hipMemsetAsync(sbuf, 0, (size_t)BB * SS * sizeof(float), stream);
    hipMemsetAsync(avec, 0, 4096 * 2, stream);
    hipMemsetAsync(out, 0, (size_t)BB * DD * sizeof(float), stream);

    bias_gemv<<<dim3(4, 16, 2), blk, 0, stream>>>(Wq, Wk, bq, bk, avec, bvec);
    dot_c<<<1, blk, 0, stream>>>(bq, bk, cbuf);
    split_x_ab<<<2048, blk, 0, stream>>>(x, xh, xl, avec, bvec, alpha, beta);
    mt_split<<<dim3(16, 16), blk, 0, stream>>>(Wk, Wq, Mth, Mtl);

    gemm_y_256<<<512, dim3(512), 0, stream>>>(xh, xl, Mth, Mtl, yh, yl);
    gemm_scores_256<<<512, dim3(512), 0, stream>>>(yh, yl, xh, xl, v,
                                                   alpha, beta, cbuf, sbuf);

    softmax_rows<<<BB, blk, 0, stream>>>(sbuf, wbuf);
    weighted_sum<<<dim3(4, BB), blk, 0, stream>>>(xh, wbuf, out);
}

// Round 12
// 539.281 us; speedup vs baseline: 1.5291x; 1.1569x over previous
//
#include <hip/hip_runtime.h>
#include <hip/hip_bf16.h>
#include <math.h>

#define BB 32
#define SS 1024
#define DD 1024

typedef __bf16 bf16_t;
typedef __bf16 bf16x2 __attribute__((ext_vector_type(2)));
typedef __bf16 bf16x4 __attribute__((ext_vector_type(4)));
typedef __bf16 bf16x8 __attribute__((ext_vector_type(8)));
typedef float f32x4 __attribute__((ext_vector_type(4)));

// async global -> LDS, 16B per lane. LDS pointer must be wave-uniform;
// HW writes lds_base + lane*16 (linear).
__device__ __forceinline__ void gload16(const void* g, void* lds_uniform) {
    __builtin_amdgcn_global_load_lds(
        (const __attribute__((address_space(1))) void*)g,
        (__attribute__((address_space(3))) void*)lds_uniform, 16, 0, 0);
}

// ---------------------------------------------------------------------------
// Stage one 256x32 bf16 tile (16 KB) into an LDS tile: 2 gloads/thread,
// 512 threads. LDS row-major [256][64B = 4 chunks of 16B], chunk-XOR
// swizzled: LDS slot (row, c) holds global chunk c ^ ((row>>1)&3)
// (verified 0 bank conflicts, round 8). Write side pre-swizzles the
// global source; LDS dest stays linear.
// ---------------------------------------------------------------------------
__device__ __forceinline__ void stage32(const bf16_t* __restrict__ src,
                                        int row0, int k0, char* tile, int tid) {
    const int r = tid >> 2;
    const int c = ((tid & 3) ^ ((tid >> 3) & 3)) * 8;   // swizzled source chunk
    char* d = tile + (tid >> 6) * 1024;   // wave-uniform dest
    const bf16_t* s = src + (size_t)(row0 + r) * DD + k0 + c;
    gload16(s, d);
    gload16(s + (size_t)128 * DD, d + 8192);
}

#define VM0  asm volatile("s_waitcnt vmcnt(0)" ::: "memory")
#define BARR asm volatile("s_barrier" ::: "memory")

// ---------------------------------------------------------------------------
// One fused K=32 column on static slot s: all three split-precision
// products (Ah*Bh + Ah*Bl + Al*Bh) from one {Ah,Al,Bh,Bl} tile group.
// Stage column c+1's 4 tiles into the other slot first (8 gloads, covered
// by ~96 MFMA/wave of compute), then 24 frag reads + 96 MFMA. One
// VM0+barrier per column (drain is covered; no intra-column barriers, so
// waves drift and overlap cross-wave).
// ---------------------------------------------------------------------------
#define COLSTEP(c, s) do {                                                    \
    if ((c) < 31) {                                                           \
        const int k1_ = ((c) + 1) * 32;                                       \
        stage32(Ahi, rowA, k1_, Lw##s + 0,     tid);                          \
        stage32(Alo, rowA, k1_, Lw##s + 16384, tid);                          \
        stage32(Bhi, rowB, k1_, Lw##s + 32768, tid);                          \
        stage32(Blo, rowB, k1_, Lw##s + 49152, tid);                          \
    }                                                                         \
    bf16x8 bh[4], bl[4];                                                      \
    _Pragma("unroll") for (int fc = 0; fc < 4; ++fc) {                        \
        bh[fc] = *(const bf16x8*)(pBh##s + fc * 1024);                        \
        bl[fc] = *(const bf16x8*)(pBl##s + fc * 1024);                        \
    }                                                                         \
    _Pragma("unroll") for (int h = 0; h < 2; ++h) {                           \
        bf16x8 ah[4], al[4];                                                  \
        _Pragma("unroll") for (int fr = 0; fr < 4; ++fr) {                    \
            ah[fr] = *(const bf16x8*)(pAh##s + h * 4096 + fr * 1024);         \
            al[fr] = *(const bf16x8*)(pAl##s + h * 4096 + fr * 1024);         \
        }                                                                     \
        _Pragma("unroll") for (int fr = 0; fr < 4; ++fr)                      \
            _Pragma("unroll") for (int fc = 0; fc < 4; ++fc) {                \
                acc[h*4+fr][fc] = __builtin_amdgcn_mfma_f32_16x16x32_bf16(    \
                    ah[fr], bh[fc], acc[h*4+fr][fc], 0, 0, 0);                \
                acc[h*4+fr][fc] = __builtin_amdgcn_mfma_f32_16x16x32_bf16(    \
                    ah[fr], bl[fc], acc[h*4+fr][fc], 0, 0, 0);                \
                acc[h*4+fr][fc] = __builtin_amdgcn_mfma_f32_16x16x32_bf16(    \
                    al[fr], bh[fc], acc[h*4+fr][fc], 0, 0, 0);                \
            }                                                                 \
    }                                                                         \
    VM0; BARR;                                                                \
} while (0)

// ---------------------------------------------------------------------------
// Fused K-loop: 32 columns of K=32, ring-2 of 64 KB tile groups
// {Ah, Al, Bh, Bl}. Slot layout: slot s at L + s*65536; tiles at
// +0 (Ah), +16384 (Al), +32768 (Bh), +49152 (Bl). Unrolled x2 so slot
// selection is static. Race-freedom: column c stages into slot s^1; all
// reads of s^1 finished before the barrier ending column c-1; VM0 before
// column c's closing barrier publishes s^1 for column c+1.
// ---------------------------------------------------------------------------
__device__ __forceinline__ void kloop_fused(
    const bf16_t* __restrict__ Ahi, const bf16_t* __restrict__ Alo,
    const bf16_t* __restrict__ Bhi, const bf16_t* __restrict__ Blo,
    int rowA, int rowB, int tid, int lane, int wm, int wn,
    char* L, f32x4 (*acc)[4])
{
    // per-lane read base: row (lane&15), k-chunk (lane>>4), chunk-XOR swizzle
    const int aoff = (lane & 15) * 64 + (((lane >> 4) ^ ((lane >> 1) & 3)) * 16);
    const char* pAh0 = L + wm * 8192 + aoff;
    const char* pAl0 = pAh0 + 16384;
    const char* pBh0 = L + 32768 + wn * 4096 + aoff;
    const char* pBl0 = pBh0 + 16384;
    const char* pAh1 = pAh0 + 65536;
    const char* pAl1 = pAl0 + 65536;
    const char* pBh1 = pBh0 + 65536;
    const char* pBl1 = pBl0 + 65536;
    char* Lw0 = L + 65536;   // writing slot 1 while reading slot 0
    char* Lw1 = L;           // writing slot 0 while reading slot 1

    // prologue: stage column 0 into slot 0
    stage32(Ahi, rowA, 0, L + 0,     tid);
    stage32(Alo, rowA, 0, L + 16384, tid);
    stage32(Bhi, rowB, 0, L + 32768, tid);
    stage32(Blo, rowB, 0, L + 49152, tid);
    VM0;
    BARR;

    for (int i = 0; i < 16; ++i) {
        COLSTEP(2 * i,     0);
        COLSTEP(2 * i + 1, 1);
    }
}

// ---------------------------------------------------------------------------
// y = x * M  (B operand = Mt[n,k] = M[k,n]); fused split-precision.
// grid 512 (1-D, XCD-swizzled): m-tile = lin>>2 (128), n-tile = lin&3 (4).
// ---------------------------------------------------------------------------
__global__ __launch_bounds__(512, 2) void gemm_y_256(
    const bf16_t* __restrict__ xh, const bf16_t* __restrict__ xl,
    const bf16_t* __restrict__ Mth, const bf16_t* __restrict__ Mtl,
    bf16_t* __restrict__ out_hi, bf16_t* __restrict__ out_lo)
{
    __shared__ __align__(16) bf16_t Lsh[2 * 4 * 256 * 32];   // 128 KB
    const int tid = threadIdx.x;
    const int lane = tid & 63, wid = tid >> 6;
    const int wm = wid >> 2, wn = wid & 3;
    const int lin = (blockIdx.x & 7) * 64 + (blockIdx.x >> 3);
    const int m0 = (lin >> 2) * 256;
    const int n0 = (lin & 3) * 256;

    f32x4 acc[8][4] = {};
    kloop_fused(xh, xl, Mth, Mtl, m0, n0, tid, lane, wm, wn,
                (char*)Lsh, acc);

    // epilogue: C/D frag layout col=lane&15, row=(lane>>4)*4+r
    const int rbase = (lane >> 4) * 4;
    const int cbase = lane & 15;
    #pragma unroll
    for (int fr = 0; fr < 8; ++fr) {
        #pragma unroll
        for (int fc = 0; fc < 4; ++fc) {
            const int n = n0 + wn * 64 + fc * 16 + cbase;
            #pragma unroll
            for (int r = 0; r < 4; ++r) {
                const int m = m0 + wm * 128 + fr * 16 + rbase + r;
                float vf = acc[fr][fc][r];
                bf16_t h = (bf16_t)vf;
                out_hi[(size_t)m * DD + n] = h;
                out_lo[(size_t)m * DD + n] = (bf16_t)(vf - (float)h);
            }
        }
    }
}

// ---------------------------------------------------------------------------
// Scores (per batch): s[b,srow] += sum_t tanh(y.x + alpha_s + beta_t + c)*v[t]
// grid 512 (XCD-swizzled): t-tile = lin&3, s-tile = (lin>>2)&3, b = lin>>4.
// ---------------------------------------------------------------------------
__global__ __launch_bounds__(512, 2) void gemm_scores_256(
    const bf16_t* __restrict__ yh, const bf16_t* __restrict__ yl,
    const bf16_t* __restrict__ xh, const bf16_t* __restrict__ xl,
    const float* __restrict__ v, const float* __restrict__ alpha,
    const float* __restrict__ beta, const float* __restrict__ cbuf,
    float* __restrict__ sbuf)
{
    __shared__ __align__(16) bf16_t Lsh[2 * 4 * 256 * 32];   // 128 KB
    const int tid = threadIdx.x;
    const int lane = tid & 63, wid = tid >> 6;
    const int wm = wid >> 2, wn = wid & 3;
    const int lin = (blockIdx.x & 7) * 64 + (blockIdx.x >> 3);
    const int t0 = (lin & 3) * 256;
    const int s0 = ((lin >> 2) & 3) * 256;
    const int b  = lin >> 4;
    const size_t boff = (size_t)b * SS * DD;

    f32x4 acc[8][4] = {};
    kloop_fused(yh + boff, yl + boff, xh + boff, xl + boff, s0, t0,
                tid, lane, wm, wn, (char*)Lsh, acc);

    // epilogue: tanh(score + alpha_s + beta_t + c)*v[t]; 16-lane col reduce.
    const float c0 = cbuf[0];
    const int rbase = (lane >> 4) * 4;
    const int cbase = lane & 15;
    float bet[4], vv[4];
    #pragma unroll
    for (int fc = 0; fc < 4; ++fc) {
        const int t = t0 + wn * 64 + fc * 16 + cbase;
        bet[fc] = beta[b * SS + t];
        vv[fc]  = v[t];
    }
    #pragma unroll
    for (int fr = 0; fr < 8; ++fr) {
        #pragma unroll
        for (int r = 0; r < 4; ++r) {
            const int srow = s0 + wm * 128 + fr * 16 + rbase + r;
            const float al = alpha[b * SS + srow] + c0;
            float p = 0.f;
            #pragma unroll
            for (int fc = 0; fc < 4; ++fc)
                p += tanhf(acc[fr][fc][r] + al + bet[fc]) * vv[fc];
            p += __shfl_xor(p, 1);
            p += __shfl_xor(p, 2);
            p += __shfl_xor(p, 4);
            p += __shfl_xor(p, 8);
            if (cbase == 0) atomicAdd(&sbuf[b * SS + srow], p);
        }
    }
}

// ---------------------------------------------------------------------------
// split x -> hi/lo bf16 AND per-row alpha = x_row.avec, beta = x_row.bvec.
// One WAVE per row (no __syncthreads); avec/bvec slices in registers.
// ---------------------------------------------------------------------------
__global__ __launch_bounds__(256) void split_x_ab(
    const float* __restrict__ src, bf16_t* __restrict__ hi,
    bf16_t* __restrict__ lo, const float* __restrict__ avec,
    const float* __restrict__ bvec, float* __restrict__ alpha,
    float* __restrict__ beta)
{
    const int lane = threadIdx.x & 63, wave = threadIdx.x >> 6;
    float4 av[4], bv[4];
    #pragma unroll
    for (int j = 0; j < 4; ++j) {
        av[j] = ((const float4*)avec)[j * 64 + lane];
        bv[j] = ((const float4*)bvec)[j * 64 + lane];
    }
    for (int row = blockIdx.x * 4 + wave; row < BB * SS; row += 2048 * 4) {
        const float4* xr = (const float4*)(src + (size_t)row * DD);
        bf16x4* hr = (bf16x4*)(hi + (size_t)row * DD);
        bf16x4* lr = (bf16x4*)(lo + (size_t)row * DD);
        float pa = 0.f, pb = 0.f;
        #pragma unroll
        for (int j = 0; j < 4; ++j) {
            float4 f = xr[j * 64 + lane];
            bf16x4 h, l;
            h.x = (bf16_t)f.x; h.y = (bf16_t)f.y;
            h.z = (bf16_t)f.z; h.w = (bf16_t)f.w;
            l.x = (bf16_t)(f.x - (float)h.x);
            l.y = (bf16_t)(f.y - (float)h.y);
            l.z = (bf16_t)(f.z - (float)h.z);
            l.w = (bf16_t)(f.w - (float)h.w);
            hr[j * 64 + lane] = h;
            lr[j * 64 + lane] = l;
            pa += f.x * av[j].x + f.y * av[j].y + f.z * av[j].z + f.w * av[j].w;
            pb += f.x * bv[j].x + f.y * bv[j].y + f.z * bv[j].z + f.w * bv[j].w;
        }
        #pragma unroll
        for (int off = 32; off; off >>= 1) {
            pa += __shfl_xor(pa, off);
            pb += __shfl_xor(pb, off);
        }
        if (lane == 0) { alpha[row] = pa; beta[row] = pb; }
    }
}

// ---------------------------------------------------------------------------
// avec[d] = sum_e Wq[e,d]*bk[e] (z=0), bvec[d] = sum_e Wk[e,d]*bq[e] (z=1).
// ---------------------------------------------------------------------------
__global__ __launch_bounds__(256) void bias_gemv(
    const float* __restrict__ Wq, const float* __restrict__ Wk,
    const float* __restrict__ bq, const float* __restrict__ bk,
    float* __restrict__ avec, float* __restrict__ bvec)
{
    const float* W   = blockIdx.z ? Wk : Wq;
    const float* bb  = blockIdx.z ? bq : bk;
    float* outv      = blockIdx.z ? bvec : avec;
    const int d  = blockIdx.x * 256 + threadIdx.x;
    const int e0 = blockIdx.y * 64;
    float s = 0.f;
    for (int e = e0; e < e0 + 64; ++e) s += W[(size_t)e * DD + d] * bb[e];
    atomicAdd(&outv[d], s);
}

__global__ __launch_bounds__(256) void dot_c(
    const float* __restrict__ bq, const float* __restrict__ bk,
    float* __restrict__ cbuf)
{
    __shared__ float red[4];
    const int tid = threadIdx.x, lane = tid & 63, wave = tid >> 6;
    float s = 0.f;
    for (int e = tid; e < DD; e += 256) s += bq[e] * bk[e];
    #pragma unroll
    for (int off = 32; off; off >>= 1) s += __shfl_xor(s, off);
    if (lane == 0) red[wave] = s;
    __syncthreads();
    if (tid == 0) cbuf[0] = red[0] + red[1] + red[2] + red[3];
}

// ---------------------------------------------------------------------------
// Mt[n,k] = sum_e Wk[e,n] * Wq[e,k] (fp32 VALU, 64x64 tile), fused bf16
// hi/lo split output.
// ---------------------------------------------------------------------------
__global__ __launch_bounds__(256) void mt_split(
    const float* __restrict__ Wk, const float* __restrict__ Wq,
    bf16_t* __restrict__ Mth, bf16_t* __restrict__ Mtl)
{
    __shared__ float Us[16][68];
    __shared__ float Vs[16][68];
    const int tid = threadIdx.x;
    const int tx = tid & 15, ty = tid >> 4;
    const int i0 = blockIdx.y * 64;
    const int j0 = blockIdx.x * 64;
    float acc[4][4] = {};
    for (int e0 = 0; e0 < DD; e0 += 16) {
        #pragma unroll
        for (int r = 0; r < 4; ++r) {
            const int kk = (tid >> 6) + r * 4;
            const int cc = tid & 63;
            Us[kk][cc] = Wk[(size_t)(e0 + kk) * DD + i0 + cc];
            Vs[kk][cc] = Wq[(size_t)(e0 + kk) * DD + j0 + cc];
        }
        __syncthreads();
        #pragma unroll
        for (int kk = 0; kk < 16; ++kk) {
            float4 a = *(const float4*)&Us[kk][ty * 4];
            float4 w = *(const float4*)&Vs[kk][tx * 4];
            acc[0][0] += a.x * w.x; acc[0][1] += a.x * w.y; acc[0][2] += a.x * w.z; acc[0][3] += a.x * w.w;
            acc[1][0] += a.y * w.x; acc[1][1] += a.y * w.y; acc[1][2] += a.y * w.z; acc[1][3] += a.y * w.w;
            acc[2][0] += a.z * w.x; acc[2][1] += a.z * w.y; acc[2][2] += a.z * w.z; acc[2][3] += a.z * w.w;
            acc[3][0] += a.w * w.x; acc[3][1] += a.w * w.y; acc[3][2] += a.w * w.z; acc[3][3] += a.w * w.w;
        }
        __syncthreads();
    }
    #pragma unroll
    for (int i = 0; i < 4; ++i) {
        #pragma unroll
        for (int j = 0; j < 4; ++j) {
            const size_t o = (size_t)(i0 + ty * 4 + i) * DD + j0 + tx * 4 + j;
            float vf = acc[i][j];
            bf16_t h = (bf16_t)vf;
            Mth[o] = h;
            Mtl[o] = (bf16_t)(vf - (float)h);
        }
    }
}

// ---------------------------------------------------------------------------
// softmax over S per batch
// ---------------------------------------------------------------------------
__global__ __launch_bounds__(256) void softmax_rows(
    const float* __restrict__ sbuf, float* __restrict__ wbuf)
{
    const int b = blockIdx.x, tid = threadIdx.x;
    const int wave = tid >> 6, lane = tid & 63;
    __shared__ float redm[4];
    __shared__ float redsum[4];

    float vals[4];
    float mx = -1e30f;
    #pragma unroll
    for (int i = 0; i < 4; ++i) {
        vals[i] = sbuf[b * SS + i * 256 + tid];
        mx = fmaxf(mx, vals[i]);
    }
    #pragma unroll
    for (int off = 32; off; off >>= 1) mx = fmaxf(mx, __shfl_xor(mx, off));
    if (lane == 0) redm[wave] = mx;
    __syncthreads();
    mx = fmaxf(fmaxf(redm[0], redm[1]), fmaxf(redm[2], redm[3]));

    float sum = 0.f;
    #pragma unroll
    for (int i = 0; i < 4; ++i) { vals[i] = expf(vals[i] - mx); sum += vals[i]; }
    #pragma unroll
    for (int off = 32; off; off >>= 1) sum += __shfl_xor(sum, off);
    if (lane == 0) redsum[wave] = sum;
    __syncthreads();
    sum = redsum[0] + redsum[1] + redsum[2] + redsum[3];

    float inv = 1.0f / sum;
    #pragma unroll
    for (int i = 0; i < 4; ++i) wbuf[b * SS + i * 256 + tid] = vals[i] * inv;
}

// ---------------------------------------------------------------------------
// out[b,d] += sum over s-chunk of w[b,s] * xh[b,s,d]  (bf16 x, s-split,
// atomicAdd partials; out zeroed by launcher).
// ---------------------------------------------------------------------------
__global__ __launch_bounds__(256) void weighted_sum(
    const bf16_t* __restrict__ xh, const float* __restrict__ wbuf,
    float* __restrict__ out)
{
    __shared__ float wl[256];
    const int b = blockIdx.y;
    const int s0 = blockIdx.x * 256;
    const int tid = threadIdx.x;
    wl[tid] = wbuf[b * SS + s0 + tid];
    __syncthreads();

    float a0 = 0.f, a1 = 0.f, a2 = 0.f, a3 = 0.f;
    const bf16_t* xb = xh + (size_t)b * SS * DD + (size_t)s0 * DD;
    #pragma unroll 4
    for (int s = 0; s < 256; ++s) {
        const bf16_t* xr = xb + (size_t)s * DD;
        bf16x2 u = *(const bf16x2*)(xr + tid * 2);
        bf16x2 w2 = *(const bf16x2*)(xr + tid * 2 + 512);
        const float w = wl[s];
        a0 += w * (float)u.x;  a1 += w * (float)u.y;
        a2 += w * (float)w2.x; a3 += w * (float)w2.y;
    }
    atomicAdd(&out[b * DD + tid * 2], a0);
    atomicAdd(&out[b * DD + tid * 2 + 1], a1);
    atomicAdd(&out[b * DD + tid * 2 + 512], a2);
    atomicAdd(&out[b * DD + tid * 2 + 513], a3);
}

// ---------------------------------------------------------------------------
extern "C" void kernel_launch(void* const* d_in, const int* in_sizes, int n_in,
                              void* d_out, int out_size, void* d_ws, size_t ws_size,
                              hipStream_t stream) {
    const float* x  = (const float*)d_in[0];
    const float* Wq = (const float*)d_in[1];
    const float* bq = (const float*)d_in[2];
    const float* Wk = (const float*)d_in[3];
    const float* bk = (const float*)d_in[4];
    const float* v  = (const float*)d_in[5];
    float* out = (float*)d_out;

    const size_t nx = (size_t)BB * SS * DD;   // 33,554,432
    const size_t nw = (size_t)DD * DD;        // 1,048,576

    dim3 blk(256);

    // workspace layout
    char* p = (char*)d_ws;
    bf16_t* xh  = (bf16_t*)p;   p += nx * 2;
    bf16_t* xl  = (bf16_t*)p;   p += nx * 2;
    bf16_t* yh  = (bf16_t*)p;   p += nx * 2;
    bf16_t* yl  = (bf16_t*)p;   p += nx * 2;
    bf16_t* Mth = (bf16_t*)p;   p += nw * 2;
    bf16_t* Mtl = (bf16_t*)p;   p += nw * 2;
    float*  avec = (float*)p;   p += 4096;
    float*  bvec = (float*)p;   p += 4096;
    float*  cbuf = (float*)p;   p += 16;
    float*  alpha = (float*)p;  p += (size_t)BB * SS * 4;
    float*  beta  = (float*)p;  p += (size_t)BB * SS * 4;
    float*  sbuf  = (float*)p;  p += (size_t)BB * SS * 4;
    float*  wbuf  = (float*)p;

    hipMemsetAsync(sbuf, 0, (size_t)BB * SS * sizeof(float), stream);
    hipMemsetAsync(avec, 0, 4096 * 2, stream);
    hipMemsetAsync(out, 0, (size_t)BB * DD * sizeof(float), stream);

    bias_gemv<<<dim3(4, 16, 2), blk, 0, stream>>>(Wq, Wk, bq, bk, avec, bvec);
    dot_c<<<1, blk, 0, stream>>>(bq, bk, cbuf);
    split_x_ab<<<2048, blk, 0, stream>>>(x, xh, xl, avec, bvec, alpha, beta);
    mt_split<<<dim3(16, 16), blk, 0, stream>>>(Wk, Wq, Mth, Mtl);

    gemm_y_256<<<512, dim3(512), 0, stream>>>(xh, xl, Mth, Mtl, yh, yl);
    gemm_scores_256<<<512, dim3(512), 0, stream>>>(yh, yl, xh, xl, v,
                                                   alpha, beta, cbuf, sbuf);

    softmax_rows<<<BB, blk, 0, stream>>>(sbuf, wbuf);
    weighted_sum<<<dim3(4, BB), blk, 0, stream>>>(xh, wbuf, out);
}